// Round 3
// baseline (121.746 us; speedup 1.0000x reference)
//
#include <hip/hip_runtime.h>

#define N_NODES 10000
#define N_EDGES 640000
#define D 128
#define NQ (N_EDGES / 4)

#define GRID1 512          // k1: 157 GEMM + 355 scatter blocks, 2 blocks/CU
#define GEMM_BLOCKS 157    // 64 nodes per block (MFMA)
#define SCAT_BLOCKS (GRID1 - GEMM_BLOCKS)   // 355
#define NBUCK 79           // bucket = row >> 7 (128 rows per bucket)
#define BCAP 10240         // records per bucket (mean 8192, +22 sigma)
#define CAP2 128           // per-row record cap (mean 64, +8 sigma)
#define QPAD2 144          // CAP2 + 16 zero-pad slots
#define OVF_CAP 8192
#define LSTR 136           // LDS row stride in ushorts: 272B, 16B-aligned

typedef unsigned int uint32;
typedef unsigned long long u64;
typedef unsigned short u16;
using short8 = __attribute__((ext_vector_type(8))) short;
using f32x4  = __attribute__((ext_vector_type(4))) float;

__device__ __forceinline__ uint32 f2bf_bits(float f) {
    uint32 u = __float_as_uint(f);
    return (u + 0x7FFFu + ((u >> 16) & 1u)) >> 16;   // RNE bf16 bits
}
__device__ __forceinline__ uint32 pack2(float lo, float hi) {
    return f2bf_bits(lo) | (f2bf_bits(hi) << 16);
}

__device__ __forceinline__ void ovf_push(int r, uint32 rc, int* ovf_cnt, u64* ovf) {
    int o = atomicAdd(ovf_cnt, 1);
    if (o < OVF_CAP)
        __hip_atomic_store(&ovf[o], ((u64)(uint32)r << 32) | rc,
                           __ATOMIC_RELAXED, __HIP_MEMORY_SCOPE_AGENT);
}

// R11: kill the per-edge global atomics (R0==R10 null + R9's ~20MB of
// unexplained RMW write traffic => scatter is atomic-op-rate-bound).
// Two-level binning: k1 buckets edges by row>>7 with LDS histograms
// (global atomics: 640K -> ~28K, one per (block,bucket)); k2 blocks scan
// their bucket's records (64KB coalesced L2 reads) and LDS-filter their
// 4 rows, then run the proven depth-8 pipelined gather. The region array,
// 8-way cursors, and big memset are deleted.
__global__ __launch_bounds__(256, 4) void gemm_scatter_kernel(
    const float* __restrict__ x, const float* __restrict__ w,
    const int* __restrict__ row, const int* __restrict__ col,
    const float* __restrict__ val,
    uint32* __restrict__ h2, int* __restrict__ gcnt,
    int* __restrict__ ovf_cnt, u64* __restrict__ ovf,
    uint2* __restrict__ bstore)
{
    __shared__ __align__(16) u16 Ws[128 * LSTR];   // 34816 B (scatter aliases)
    const int t = threadIdx.x;
    const int lane = t & 63;
    const int wid  = t >> 6;

    if (blockIdx.x < GEMM_BLOCKS) {
        // ---- MFMA GEMM: 64 rows/block, 4 waves x 16 rows x 128 cols.
        // A loaded directly global->reg; W staged col-major in LDS.
        // C/D: col=lane&15, row=quad*4+reg (HW-verified).
        const int q = lane >> 4, cl = lane & 15;

        #pragma unroll
        for (int i = 0; i < 32; ++i) {                // stage W^T (128x128)
            int lin = t + i * 256;
            int c = lin & 127;
            int m = lin >> 7;
            float w0 = w[(2 * m) * D + c];
            float w1 = w[(2 * m + 1) * D + c];
            *(uint32*)&Ws[c * LSTR + 2 * m] = pack2(w0, w1);
        }

        int gr = blockIdx.x * 64 + wid * 16 + cl;     // A-fragment row
        if (gr >= N_NODES) gr = N_NODES - 1;          // tail clamp (guarded write)
        const float* xrow = &x[(size_t)gr * D];
        float4 xv[8];
        #pragma unroll
        for (int kk = 0; kk < 4; ++kk) {
            xv[2 * kk]     = *(const float4*)&xrow[kk * 32 + q * 8];
            xv[2 * kk + 1] = *(const float4*)&xrow[kk * 32 + q * 8 + 4];
        }
        __syncthreads();

        f32x4 acc[8] = {};
        #pragma unroll
        for (int kk = 0; kk < 4; ++kk) {
            union { short8 s; uint32 u[4]; } af;
            float4 a = xv[2 * kk], b = xv[2 * kk + 1];
            af.u[0] = pack2(a.x, a.y); af.u[1] = pack2(a.z, a.w);
            af.u[2] = pack2(b.x, b.y); af.u[3] = pack2(b.z, b.w);
            #pragma unroll
            for (int ct = 0; ct < 8; ++ct) {
                short8 bf = *(const short8*)&Ws[(ct * 16 + cl) * LSTR + kk * 32 + q * 8];
                acc[ct] = __builtin_amdgcn_mfma_f32_16x16x32_bf16(af.s, bf, acc[ct], 0, 0, 0);
            }
        }
        #pragma unroll
        for (int reg = 0; reg < 4; ++reg) {
            int node = blockIdx.x * 64 + wid * 16 + q * 4 + reg;
            if (node < N_NODES) {
                uint32* base = h2 + (size_t)node * 64 + cl;
                #pragma unroll
                for (int ct = 0; ct < 4; ++ct)
                    base[ct * 16] = pack2(acc[ct][reg], acc[ct + 4][reg]);
            }
        }
    } else {
        // ---- Bucket scatter: LDS histogram -> 1 global atomic per bucket ----
        int* lcnt  = (int*)Ws;            // [96]  counts
        int* lbase = (int*)Ws + 96;       // [96]  global bases
        int* lcnt2 = (int*)Ws + 192;      // [96]  place-pass counters
        if (t < NBUCK) lcnt[t] = 0;
        __syncthreads();

        const int sb = blockIdx.x - GEMM_BLOCKS;
        const int4*   row4 = (const int4*)row;
        const int4*   col4 = (const int4*)col;
        const float4* val4 = (const float4*)val;

        // pass A: count rows into buckets (LDS atomics only)
        for (int i = sb * 256 + t; i < NQ; i += SCAT_BLOCKS * 256) {
            int4 r = row4[i];
            atomicAdd(&lcnt[r.x >> 7], 1);
            atomicAdd(&lcnt[r.y >> 7], 1);
            atomicAdd(&lcnt[r.z >> 7], 1);
            atomicAdd(&lcnt[r.w >> 7], 1);
        }
        __syncthreads();
        if (t < NBUCK) {
            int c = lcnt[t];
            lbase[t] = (c > 0) ? atomicAdd(&gcnt[t], c) : 0;   // ~28K total
            lcnt2[t] = 0;
        }
        __syncthreads();

        // pass B: place records (edge list re-read is L2-hot)
        for (int i = sb * 256 + t; i < NQ; i += SCAT_BLOCKS * 256) {
            int4 r = row4[i]; int4 c = col4[i]; float4 v = val4[i];
            #pragma unroll
            for (int e = 0; e < 4; ++e) {
                int rr = (e == 0) ? r.x : (e == 1) ? r.y : (e == 2) ? r.z : r.w;
                int cc = (e == 0) ? c.x : (e == 1) ? c.y : (e == 2) ? c.z : c.w;
                float vv = (e == 0) ? v.x : (e == 1) ? v.y : (e == 2) ? v.z : v.w;
                uint32 rc = (uint32)cc | (f2bf_bits(vv) << 16);
                int b = rr >> 7;
                int k = atomicAdd(&lcnt2[b], 1);          // LDS
                int pos = lbase[b] + k;
                if (pos < BCAP)
                    bstore[(size_t)b * BCAP + pos] = make_uint2(rc, (uint32)rr);
                else
                    ovf_push(rr, rc, ovf_cnt, ovf);       // ~never (+22 sigma)
            }
        }
    }
}

// k2: per block (4 rows, all in one bucket since 128%4==0): scan the bucket's
// records, LDS-filter own rows into per-wave queues, zero-pad, then the proven
// branch-free depth-8 software-pipelined gather (8 L2 gathers in flight).
__global__ __launch_bounds__(256) void spmm_kernel(
    const uint2* __restrict__ bstore, const int* __restrict__ gcnt,
    int* __restrict__ ovf_cnt, u64* __restrict__ ovf,
    const uint32* __restrict__ h2, const float* __restrict__ bias,
    float* __restrict__ out)
{
    __shared__ uint32 qbuf[4 * QPAD2];    // per-wave row queues (2304 B)
    __shared__ int cnt[4];
    const int t = threadIdx.x;
    const int lane = t & 63;
    const int wid  = t >> 6;
    const int r0 = blockIdx.x * 4;
    const int b  = r0 >> 7;

    if (t < 4) cnt[t] = 0;
    __syncthreads();

    int n = gcnt[b]; if (n > BCAP) n = BCAP;
    for (int i = t; i < n; i += 256) {
        uint2 e = bstore[(size_t)b * BCAP + i];     // coalesced 8B
        uint32 d = e.y - (uint32)r0;
        if (d < 4u) {
            int k = atomicAdd(&cnt[d], 1);          // LDS
            if (k < CAP2) qbuf[d * QPAD2 + k] = e.x;
            else ovf_push((int)e.y, e.x, ovf_cnt, ovf);  // ~never (+8 sigma)
        }
    }
    __syncthreads();

    const int r = r0 + wid;
    uint32* qb = &qbuf[wid * QPAD2];
    int ntot = cnt[wid]; if (ntot > CAP2) ntot = CAP2;
    if (lane < 16) qb[ntot + lane] = 0;        // zero pad (val=+0.0 recs)
    __builtin_amdgcn_s_waitcnt(0);             // drain LDS writes (wave-local)

    const int npad = (ntot + 7) & ~7;
    float a0 = 0.f, a1 = 0.f;

    uint32 rq0,rq1,rq2,rq3,rq4,rq5,rq6,rq7;
    uint32 hh0,hh1,hh2,hh3,hh4,hh5,hh6,hh7;
    rq0 = qb[0]; hh0 = h2[((rq0 & 0xFFFFu) << 6) + lane];
    rq1 = qb[1]; hh1 = h2[((rq1 & 0xFFFFu) << 6) + lane];
    rq2 = qb[2]; hh2 = h2[((rq2 & 0xFFFFu) << 6) + lane];
    rq3 = qb[3]; hh3 = h2[((rq3 & 0xFFFFu) << 6) + lane];
    rq4 = qb[4]; hh4 = h2[((rq4 & 0xFFFFu) << 6) + lane];
    rq5 = qb[5]; hh5 = h2[((rq5 & 0xFFFFu) << 6) + lane];
    rq6 = qb[6]; hh6 = h2[((rq6 & 0xFFFFu) << 6) + lane];
    rq7 = qb[7]; hh7 = h2[((rq7 & 0xFFFFu) << 6) + lane];

#define CONSUME_PREFETCH(RQ, HH, P)                                          \
    {                                                                        \
        a0 = fmaf(__uint_as_float(RQ & 0xFFFF0000u),                         \
                  __uint_as_float(HH << 16), a0);                            \
        a1 = fmaf(__uint_as_float(RQ & 0xFFFF0000u),                         \
                  __uint_as_float(HH & 0xFFFF0000u), a1);                    \
        uint32 rn = qb[j + 8 + P];                                           \
        RQ = rn; HH = h2[((rn & 0xFFFFu) << 6) + lane];                      \
    }

    for (int j = 0; j < npad; j += 8) {
        CONSUME_PREFETCH(rq0, hh0, 0)
        CONSUME_PREFETCH(rq1, hh1, 1)
        CONSUME_PREFETCH(rq2, hh2, 2)
        CONSUME_PREFETCH(rq3, hh3, 3)
        CONSUME_PREFETCH(rq4, hh4, 4)
        CONSUME_PREFETCH(rq5, hh5, 5)
        CONSUME_PREFETCH(rq6, hh6, 6)
        CONSUME_PREFETCH(rq7, hh7, 7)
    }
#undef CONSUME_PREFETCH

    // overflow list (expected empty; agent-scope loads for k2-self appends)
    int novf = __hip_atomic_load(ovf_cnt, __ATOMIC_RELAXED, __HIP_MEMORY_SCOPE_AGENT);
    if (novf > OVF_CAP) novf = OVF_CAP;
    for (int k = 0; k < novf; ++k) {
        u64 e = __hip_atomic_load(&ovf[k], __ATOMIC_RELAXED, __HIP_MEMORY_SCOPE_AGENT);
        if ((uint32)(e >> 32) == (uint32)r) {
            uint32 qq = (uint32)e;
            uint32 hv = h2[((qq & 0xFFFFu) << 6) + lane];
            a0 = fmaf(__uint_as_float(qq & 0xFFFF0000u), __uint_as_float(hv << 16), a0);
            a1 = fmaf(__uint_as_float(qq & 0xFFFF0000u), __uint_as_float(hv & 0xFFFF0000u), a1);
        }
    }

    out[(size_t)r * D + lane]      = a0 + bias[lane];
    out[(size_t)r * D + 64 + lane] = a1 + bias[lane + 64];
}

extern "C" void kernel_launch(void* const* d_in, const int* in_sizes, int n_in,
                              void* d_out, int out_size, void* d_ws, size_t ws_size,
                              hipStream_t stream)
{
    const float* x    = (const float*)d_in[0];
    const float* aval = (const float*)d_in[1];
    const float* w    = (const float*)d_in[2];
    const float* bias = (const float*)d_in[3];
    const int* arow   = (const int*)d_in[4];
    const int* acol   = (const int*)d_in[5];

    char* ws = (char*)d_ws;
    uint32* h2     = (uint32*)(ws);               //  2,560,000 B
    int*    gcnt   = (int*)(ws + 2560000);        //        320 B (79 buckets)
    int*    ovfcnt = (int*)(ws + 2560320);        //          4 B
    u64*    ovf    = (u64*)(ws + 2560384);        //     65,536 B
    uint2*  bstore = (uint2*)(ws + 2625920);      //  6,471,680 B (79 x 10240 x 8)

    hipMemsetAsync(ws + 2560000, 0, 324, stream);  // gcnt + ovf_cnt only

    gemm_scatter_kernel<<<GRID1, 256, 0, stream>>>(
        x, w, arow, acol, aval, h2, gcnt, ovfcnt, ovf, bstore);
    spmm_kernel<<<N_NODES / 4, 256, 0, stream>>>(
        bstore, gcnt, ovfcnt, ovf, h2, bias, (float*)d_out);
}